// Round 1
// baseline (656.105 us; speedup 1.0000x reference)
//
#include <hip/hip_runtime.h>
#include <hip/hip_bf16.h>

typedef __bf16 bf16x8 __attribute__((ext_vector_type(8)));
typedef float f32x4 __attribute__((ext_vector_type(4)));

#define T_TOK 4096
#define H_DIM 1024
#define F_DIM 2048
#define NEXP 8
#define TOTROWS 8192   // T_TOK * TOP_K, always exact (top-2 distinct experts)
#define MAXTILES 80
#define LDK 40         // LDS row stride in bf16 elems (80 B): 16B-aligned, 2-way-free banks

__device__ inline unsigned short f2b(float f) {
    // RTNE float -> bf16 bits (inputs finite)
    unsigned int u = __float_as_uint(f);
    unsigned int r = (u + 0x7fffu + ((u >> 16) & 1u)) >> 16;
    return (unsigned short)r;
}

// ---------------- zero out + meta counters ----------------
__global__ __launch_bounds__(256) void zero_kernel(float* __restrict__ out, int* __restrict__ meta) {
    int idx = blockIdx.x * 256 + threadIdx.x;
    ((float4*)out)[idx] = make_float4(0.f, 0.f, 0.f, 0.f);
    if (blockIdx.x == 0 && threadIdx.x < 16) meta[threadIdx.x] = 0;  // cnt[8] + fill[8]
}

// ---------------- router: logits -> softmax -> top2 -> renorm ----------------
__global__ __launch_bounds__(64) void router_kernel(const float* __restrict__ x,
                                                    const float* __restrict__ gw,
                                                    int* __restrict__ sel, float* __restrict__ selw,
                                                    int* __restrict__ cnt) {
    int t = blockIdx.x;
    int lane = threadIdx.x;
    float acc[8] = {0.f,0.f,0.f,0.f,0.f,0.f,0.f,0.f};
    const float* xr = x + (size_t)t * H_DIM;
    for (int h = lane; h < H_DIM; h += 64) {
        float xv = xr[h];
        const float4* g = (const float4*)(gw + h * 8);
        float4 g0 = g[0], g1 = g[1];
        acc[0] += xv * g0.x; acc[1] += xv * g0.y; acc[2] += xv * g0.z; acc[3] += xv * g0.w;
        acc[4] += xv * g1.x; acc[5] += xv * g1.y; acc[6] += xv * g1.z; acc[7] += xv * g1.w;
    }
#pragma unroll
    for (int off = 32; off >= 1; off >>= 1)
#pragma unroll
        for (int e = 0; e < 8; ++e)
            acc[e] += __shfl_down(acc[e], off);
    if (lane == 0) {
        float mx = acc[0];
#pragma unroll
        for (int e = 1; e < 8; ++e) mx = fmaxf(mx, acc[e]);
        float p[8]; float s = 0.f;
#pragma unroll
        for (int e = 0; e < 8; ++e) { p[e] = expf(acc[e] - mx); s += p[e]; }
        float inv_s = 1.f / s;
#pragma unroll
        for (int e = 0; e < 8; ++e) p[e] *= inv_s;
        int e1 = 0; float p1 = p[0];
#pragma unroll
        for (int e = 1; e < 8; ++e) if (p[e] > p1) { p1 = p[e]; e1 = e; }
        int e2 = -1; float p2 = -1.f;
#pragma unroll
        for (int e = 0; e < 8; ++e) { if (e == e1) continue; if (p[e] > p2) { p2 = p[e]; e2 = e; } }
        float inv = 1.f / (p1 + p2);
        sel[t * 2 + 0] = e1; sel[t * 2 + 1] = e2;
        selw[t * 2 + 0] = p1 * inv; selw[t * 2 + 1] = p2 * inv;
        atomicAdd(&cnt[e1], 1); atomicAdd(&cnt[e2], 1);
    }
}

// ---------------- prefix scan + tile table (single thread; trivial) ----------------
__global__ void scan_kernel(const int* __restrict__ cnt, int* __restrict__ off,
                            int* __restrict__ tileExp, int* __restrict__ tileM0) {
    if (blockIdx.x == 0 && threadIdx.x == 0) {
        int o = 0;
        for (int e = 0; e < NEXP; ++e) { off[e] = o; o += cnt[e]; }
        int nt = 0;
        for (int e = 0; e < NEXP; ++e)
            for (int m0 = 0; m0 < cnt[e]; m0 += 128) { tileExp[nt] = e; tileM0[nt] = m0; nt++; }
        for (int i = nt; i < MAXTILES; ++i) { tileExp[i] = -1; tileM0[i] = 0; }
    }
}

// ---------------- scatter: build compacted row lists ----------------
__global__ __launch_bounds__(256) void scatter_kernel(const int* __restrict__ sel,
                                                      const float* __restrict__ selw,
                                                      const int* __restrict__ off,
                                                      int* __restrict__ fill,
                                                      int* __restrict__ rowTok, float* __restrict__ rowWgt) {
    int t = blockIdx.x * 256 + threadIdx.x;
    if (t >= T_TOK) return;
#pragma unroll
    for (int k = 0; k < 2; ++k) {
        int e = sel[t * 2 + k];
        int slot = atomicAdd(&fill[e], 1);
        int r = off[e] + slot;
        rowTok[r] = t;
        rowWgt[r] = selw[t * 2 + k];
    }
}

// ---------------- gather: x rows (fp32) -> Xg (bf16), compacted order ----------------
__global__ __launch_bounds__(256) void gather_kernel(const float* __restrict__ x,
                                                     const int* __restrict__ rowTok,
                                                     unsigned short* __restrict__ Xg) {
    int r = blockIdx.x;
    int t = rowTok[r];
    const float4* src = (const float4*)(x + (size_t)t * H_DIM);
    int i = threadIdx.x;               // 256 threads x 4 floats = 1024
    float4 v = src[i];
    ushort4 o;
    o.x = f2b(v.x); o.y = f2b(v.y); o.z = f2b(v.z); o.w = f2b(v.w);
    ((ushort4*)(Xg + (size_t)r * H_DIM))[i] = o;
}

// ---------------- transpose + fp32->bf16: src [E][R][C] -> dst [E][C][R] ----------------
__global__ __launch_bounds__(256) void transpose_cvt_kernel(const float* __restrict__ src,
                                                            unsigned short* __restrict__ dst,
                                                            int R, int C) {
    __shared__ float tile[32][33];
    int e = blockIdx.z;
    const float* s = src + (size_t)e * R * C;
    unsigned short* d = dst + (size_t)e * R * C;
    int tx = threadIdx.x, ty = threadIdx.y;  // 32 x 8
    int c0 = blockIdx.x * 32, r0 = blockIdx.y * 32;
#pragma unroll
    for (int i = 0; i < 4; ++i)
        tile[ty + i * 8][tx] = s[(size_t)(r0 + ty + i * 8) * C + c0 + tx];
    __syncthreads();
#pragma unroll
    for (int i = 0; i < 4; ++i)
        d[(size_t)(c0 + ty + i * 8) * R + r0 + tx] = f2b(tile[tx][ty + i * 8]);
}

// ---------------- fused up/gate GEMM + silu epilogue ----------------
// C_up = Xg[M,K=H] * wTu^T, C_gate likewise; inner = silu(up)*gate (bf16)
__global__ __launch_bounds__(256, 2) void gemm_upgate_kernel(
        const unsigned short* __restrict__ Xg,
        const unsigned short* __restrict__ wTu,   // [E][F][H] (k-major)
        const unsigned short* __restrict__ wTg,
        unsigned short* __restrict__ inner,       // [TOTROWS][F]
        const int* __restrict__ tileExp, const int* __restrict__ tileM0,
        const int* __restrict__ off, const int* __restrict__ cnt) {
    __shared__ __align__(16) unsigned short la[128 * LDK];
    __shared__ __align__(16) unsigned short lbu[128 * LDK];
    __shared__ __align__(16) unsigned short lbg[128 * LDK];
    int bt = blockIdx.y;
    int e = tileExp[bt];
    if (e < 0) return;
    int m0 = tileM0[bt];
    int r0 = off[e] + m0;
    int valid = cnt[e] - m0;
    int f0 = blockIdx.x * 128;
    const unsigned short* bu = wTu + (size_t)e * F_DIM * H_DIM + (size_t)f0 * H_DIM;
    const unsigned short* bg = wTg + (size_t)e * F_DIM * H_DIM + (size_t)f0 * H_DIM;
    int tid = threadIdx.x;
    int lane = tid & 63, wid = tid >> 6;
    int wm = wid >> 1, wn = wid & 1;
    int l16 = lane & 15, quad = lane >> 4;
    f32x4 accU[4][4], accG[4][4];
#pragma unroll
    for (int i = 0; i < 4; ++i)
#pragma unroll
        for (int j = 0; j < 4; ++j) { accU[i][j] = (f32x4)0.f; accG[i][j] = (f32x4)0.f; }

    for (int k0 = 0; k0 < H_DIM; k0 += 32) {
        __syncthreads();
#pragma unroll
        for (int it = 0; it < 2; ++it) {
            int cidx = tid + it * 256;
            int row = cidx >> 2, kc = cidx & 3;
            uint4 va = make_uint4(0u, 0u, 0u, 0u);
            if (row < valid) va = *(const uint4*)(Xg + (size_t)(r0 + row) * H_DIM + k0 + kc * 8);
            *(uint4*)&la[row * LDK + kc * 8] = va;
            *(uint4*)&lbu[row * LDK + kc * 8] = *(const uint4*)(bu + (size_t)row * H_DIM + k0 + kc * 8);
            *(uint4*)&lbg[row * LDK + kc * 8] = *(const uint4*)(bg + (size_t)row * H_DIM + k0 + kc * 8);
        }
        __syncthreads();
        bf16x8 af[4], bfu[4], bfg[4];
#pragma unroll
        for (int i = 0; i < 4; ++i)
            af[i] = *(const bf16x8*)&la[(wm * 64 + i * 16 + l16) * LDK + quad * 8];
#pragma unroll
        for (int j = 0; j < 4; ++j) {
            bfu[j] = *(const bf16x8*)&lbu[(wn * 64 + j * 16 + l16) * LDK + quad * 8];
            bfg[j] = *(const bf16x8*)&lbg[(wn * 64 + j * 16 + l16) * LDK + quad * 8];
        }
#pragma unroll
        for (int i = 0; i < 4; ++i)
#pragma unroll
            for (int j = 0; j < 4; ++j) {
                accU[i][j] = __builtin_amdgcn_mfma_f32_16x16x32_bf16(af[i], bfu[j], accU[i][j], 0, 0, 0);
                accG[i][j] = __builtin_amdgcn_mfma_f32_16x16x32_bf16(af[i], bfg[j], accG[i][j], 0, 0, 0);
            }
    }
#pragma unroll
    for (int i = 0; i < 4; ++i) {
#pragma unroll
        for (int rr = 0; rr < 4; ++rr) {
            int ml = wm * 64 + i * 16 + quad * 4 + rr;
            if (ml >= valid) continue;
            size_t base = (size_t)(r0 + ml) * F_DIM + f0;
#pragma unroll
            for (int j = 0; j < 4; ++j) {
                float u = accU[i][j][rr];
                float g = accG[i][j][rr];
                float v = u / (1.f + expf(-u)) * g;   // silu(up) * gate
                inner[base + wn * 64 + j * 16 + l16] = f2b(v);
            }
        }
    }
}

// ---------------- down GEMM + weighted atomic scatter ----------------
__global__ __launch_bounds__(256, 2) void gemm_down_kernel(
        const unsigned short* __restrict__ inner,  // [TOTROWS][F]
        const unsigned short* __restrict__ wTd,    // [E][H][F] (k-major)
        float* __restrict__ out,
        const int* __restrict__ tileExp, const int* __restrict__ tileM0,
        const int* __restrict__ off, const int* __restrict__ cnt,
        const int* __restrict__ rowTok, const float* __restrict__ rowWgt) {
    __shared__ __align__(16) unsigned short la[128 * LDK];
    __shared__ __align__(16) unsigned short lb[128 * LDK];
    int bt = blockIdx.y;
    int e = tileExp[bt];
    if (e < 0) return;
    int m0 = tileM0[bt];
    int r0 = off[e] + m0;
    int valid = cnt[e] - m0;
    int h0 = blockIdx.x * 128;
    const unsigned short* bp = wTd + (size_t)e * H_DIM * F_DIM + (size_t)h0 * F_DIM;
    int tid = threadIdx.x;
    int lane = tid & 63, wid = tid >> 6;
    int wm = wid >> 1, wn = wid & 1;
    int l16 = lane & 15, quad = lane >> 4;
    f32x4 acc[4][4];
#pragma unroll
    for (int i = 0; i < 4; ++i)
#pragma unroll
        for (int j = 0; j < 4; ++j) acc[i][j] = (f32x4)0.f;

    for (int k0 = 0; k0 < F_DIM; k0 += 32) {
        __syncthreads();
#pragma unroll
        for (int it = 0; it < 2; ++it) {
            int cidx = tid + it * 256;
            int row = cidx >> 2, kc = cidx & 3;
            uint4 va = make_uint4(0u, 0u, 0u, 0u);
            if (row < valid) va = *(const uint4*)(inner + (size_t)(r0 + row) * F_DIM + k0 + kc * 8);
            *(uint4*)&la[row * LDK + kc * 8] = va;
            *(uint4*)&lb[row * LDK + kc * 8] = *(const uint4*)(bp + (size_t)row * F_DIM + k0 + kc * 8);
        }
        __syncthreads();
        bf16x8 af[4], bf[4];
#pragma unroll
        for (int i = 0; i < 4; ++i)
            af[i] = *(const bf16x8*)&la[(wm * 64 + i * 16 + l16) * LDK + quad * 8];
#pragma unroll
        for (int j = 0; j < 4; ++j)
            bf[j] = *(const bf16x8*)&lb[(wn * 64 + j * 16 + l16) * LDK + quad * 8];
#pragma unroll
        for (int i = 0; i < 4; ++i)
#pragma unroll
            for (int j = 0; j < 4; ++j)
                acc[i][j] = __builtin_amdgcn_mfma_f32_16x16x32_bf16(af[i], bf[j], acc[i][j], 0, 0, 0);
    }
#pragma unroll
    for (int i = 0; i < 4; ++i) {
#pragma unroll
        for (int rr = 0; rr < 4; ++rr) {
            int ml = wm * 64 + i * 16 + quad * 4 + rr;
            if (ml >= valid) continue;
            int gr = r0 + ml;
            int t = rowTok[gr];
            float w = rowWgt[gr];
            float* orow = out + (size_t)t * H_DIM + h0;
#pragma unroll
            for (int j = 0; j < 4; ++j)
                atomicAdd(&orow[wn * 64 + j * 16 + l16], w * acc[i][j][rr]);
        }
    }
}

extern "C" void kernel_launch(void* const* d_in, const int* in_sizes, int n_in,
                              void* d_out, int out_size, void* d_ws, size_t ws_size,
                              hipStream_t stream) {
    const float* x      = (const float*)d_in[0];
    const float* gw     = (const float*)d_in[1];
    const float* w_up   = (const float*)d_in[2];
    const float* w_gate = (const float*)d_in[3];
    const float* w_down = (const float*)d_in[4];
    float* out = (float*)d_out;

    char* ws = (char*)d_ws;
    size_t o = 0;
    unsigned short* wTu = (unsigned short*)(ws + o); o += (size_t)NEXP * F_DIM * H_DIM * 2;
    unsigned short* wTg = (unsigned short*)(ws + o); o += (size_t)NEXP * F_DIM * H_DIM * 2;
    unsigned short* wTd = (unsigned short*)(ws + o); o += (size_t)NEXP * H_DIM * F_DIM * 2;
    unsigned short* Xg  = (unsigned short*)(ws + o); o += (size_t)TOTROWS * H_DIM * 2;
    unsigned short* inner = (unsigned short*)(ws + o); o += (size_t)TOTROWS * F_DIM * 2;
    int*   rowTok = (int*)(ws + o);   o += TOTROWS * 4;
    float* rowWgt = (float*)(ws + o); o += TOTROWS * 4;
    int*   sel    = (int*)(ws + o);   o += T_TOK * 2 * 4;
    float* selw   = (float*)(ws + o); o += T_TOK * 2 * 4;
    int*   cnt    = (int*)(ws + o);   o += 8 * 4;   // cnt[8] then fill[8] contiguous
    int*   fill   = (int*)(ws + o);   o += 8 * 4;
    int*   off_   = (int*)(ws + o);   o += 8 * 4;
    int*   tileExp = (int*)(ws + o);  o += MAXTILES * 4;
    int*   tileM0  = (int*)(ws + o);  o += MAXTILES * 4;

    zero_kernel<<<4096, 256, 0, stream>>>(out, cnt);  // zeros out + cnt/fill
    router_kernel<<<T_TOK, 64, 0, stream>>>(x, gw, sel, selw, cnt);
    scan_kernel<<<1, 64, 0, stream>>>(cnt, off_, tileExp, tileM0);
    scatter_kernel<<<T_TOK / 256, 256, 0, stream>>>(sel, selw, off_, fill, rowTok, rowWgt);
    gather_kernel<<<TOTROWS, 256, 0, stream>>>(x, rowTok, Xg);
    dim3 tb(32, 8, 1);
    transpose_cvt_kernel<<<dim3(F_DIM / 32, H_DIM / 32, NEXP), tb, 0, stream>>>(w_up, wTu, H_DIM, F_DIM);
    transpose_cvt_kernel<<<dim3(F_DIM / 32, H_DIM / 32, NEXP), tb, 0, stream>>>(w_gate, wTg, H_DIM, F_DIM);
    transpose_cvt_kernel<<<dim3(H_DIM / 32, F_DIM / 32, NEXP), tb, 0, stream>>>(w_down, wTd, F_DIM, H_DIM);
    gemm_upgate_kernel<<<dim3(F_DIM / 128, 72), 256, 0, stream>>>(Xg, wTu, wTg, inner, tileExp, tileM0, off_, cnt);
    gemm_down_kernel<<<dim3(H_DIM / 128, 72), 256, 0, stream>>>(inner, wTd, out, tileExp, tileM0, off_, cnt, rowTok, rowWgt);
}

// Round 2
// 585.745 us; speedup vs baseline: 1.1201x; 1.1201x over previous
//
#include <hip/hip_runtime.h>
#include <hip/hip_bf16.h>

typedef __bf16 bf16x8 __attribute__((ext_vector_type(8)));
typedef float f32x4 __attribute__((ext_vector_type(4)));

#define T_TOK 4096
#define H_DIM 1024
#define F_DIM 2048
#define NEXP 8
#define TOTROWS 8192   // T_TOK * TOP_K, always exact (top-2 distinct experts)
#define MAXTILES 80

__device__ inline unsigned short f2b(float f) {
    unsigned int u = __float_as_uint(f);
    unsigned int r = (u + 0x7fffu + ((u >> 16) & 1u)) >> 16;
    return (unsigned short)r;
}

// async global->LDS, 16B per lane. LDS dst = wave-uniform base + lane*16.
__device__ inline void gload16(const void* g, void* l) {
    __builtin_amdgcn_global_load_lds(
        (const __attribute__((address_space(1))) unsigned int*)g,
        (__attribute__((address_space(3))) unsigned int*)l,
        16, 0, 0);
}

// ---------------- zero out + meta counters ----------------
__global__ __launch_bounds__(256) void zero_kernel(float* __restrict__ out, int* __restrict__ meta) {
    int idx = blockIdx.x * 256 + threadIdx.x;
    ((float4*)out)[idx] = make_float4(0.f, 0.f, 0.f, 0.f);
    if (blockIdx.x == 0 && threadIdx.x < 16) meta[threadIdx.x] = 0;  // cnt[8] + fill[8]
}

// ---------------- router: logits -> softmax -> top2 -> renorm ----------------
__global__ __launch_bounds__(64) void router_kernel(const float* __restrict__ x,
                                                    const float* __restrict__ gw,
                                                    int* __restrict__ sel, float* __restrict__ selw,
                                                    int* __restrict__ cnt) {
    int t = blockIdx.x;
    int lane = threadIdx.x;
    float acc[8] = {0.f,0.f,0.f,0.f,0.f,0.f,0.f,0.f};
    const float* xr = x + (size_t)t * H_DIM;
    for (int h = lane; h < H_DIM; h += 64) {
        float xv = xr[h];
        const float4* g = (const float4*)(gw + h * 8);
        float4 g0 = g[0], g1 = g[1];
        acc[0] += xv * g0.x; acc[1] += xv * g0.y; acc[2] += xv * g0.z; acc[3] += xv * g0.w;
        acc[4] += xv * g1.x; acc[5] += xv * g1.y; acc[6] += xv * g1.z; acc[7] += xv * g1.w;
    }
#pragma unroll
    for (int off = 32; off >= 1; off >>= 1)
#pragma unroll
        for (int e = 0; e < 8; ++e)
            acc[e] += __shfl_down(acc[e], off);
    if (lane == 0) {
        float mx = acc[0];
#pragma unroll
        for (int e = 1; e < 8; ++e) mx = fmaxf(mx, acc[e]);
        float p[8]; float s = 0.f;
#pragma unroll
        for (int e = 0; e < 8; ++e) { p[e] = expf(acc[e] - mx); s += p[e]; }
        float inv_s = 1.f / s;
#pragma unroll
        for (int e = 0; e < 8; ++e) p[e] *= inv_s;
        int e1 = 0; float p1 = p[0];
#pragma unroll
        for (int e = 1; e < 8; ++e) if (p[e] > p1) { p1 = p[e]; e1 = e; }
        int e2 = -1; float p2 = -1.f;
#pragma unroll
        for (int e = 0; e < 8; ++e) { if (e == e1) continue; if (p[e] > p2) { p2 = p[e]; e2 = e; } }
        float inv = 1.f / (p1 + p2);
        sel[t * 2 + 0] = e1; sel[t * 2 + 1] = e2;
        selw[t * 2 + 0] = p1 * inv; selw[t * 2 + 1] = p2 * inv;
        atomicAdd(&cnt[e1], 1); atomicAdd(&cnt[e2], 1);
    }
}

// ---------------- prefix scan + tile table ----------------
__global__ void scan_kernel(const int* __restrict__ cnt, int* __restrict__ off,
                            int* __restrict__ tileExp, int* __restrict__ tileM0) {
    if (blockIdx.x == 0 && threadIdx.x == 0) {
        int o = 0;
        for (int e = 0; e < NEXP; ++e) { off[e] = o; o += cnt[e]; }
        int nt = 0;
        for (int e = 0; e < NEXP; ++e)
            for (int m0 = 0; m0 < cnt[e]; m0 += 128) { tileExp[nt] = e; tileM0[nt] = m0; nt++; }
        for (int i = nt; i < MAXTILES; ++i) { tileExp[i] = -1; tileM0[i] = 0; }
    }
}

// ---------------- scatter: build compacted row lists ----------------
__global__ __launch_bounds__(256) void scatter_kernel(const int* __restrict__ sel,
                                                      const float* __restrict__ selw,
                                                      const int* __restrict__ off,
                                                      int* __restrict__ fill,
                                                      int* __restrict__ rowTok, float* __restrict__ rowWgt) {
    int t = blockIdx.x * 256 + threadIdx.x;
    if (t >= T_TOK) return;
#pragma unroll
    for (int k = 0; k < 2; ++k) {
        int e = sel[t * 2 + k];
        int slot = atomicAdd(&fill[e], 1);
        int r = off[e] + slot;
        rowTok[r] = t;
        rowWgt[r] = selw[t * 2 + k];
    }
}

// ---------------- gather: x rows (fp32) -> Xg (bf16), compacted order ----------------
__global__ __launch_bounds__(256) void gather_kernel(const float* __restrict__ x,
                                                     const int* __restrict__ rowTok,
                                                     unsigned short* __restrict__ Xg) {
    int r = blockIdx.x;
    int t = rowTok[r];
    const float4* src = (const float4*)(x + (size_t)t * H_DIM);
    int i = threadIdx.x;
    float4 v = src[i];
    ushort4 o;
    o.x = f2b(v.x); o.y = f2b(v.y); o.z = f2b(v.z); o.w = f2b(v.w);
    ((ushort4*)(Xg + (size_t)r * H_DIM))[i] = o;
}

// ---------------- transpose + fp32->bf16: src [E][R][C] -> dst [E][C][R] ----------------
__global__ __launch_bounds__(256) void transpose_cvt_kernel(const float* __restrict__ src,
                                                            unsigned short* __restrict__ dst,
                                                            int R, int C) {
    __shared__ float tile[32][33];
    int e = blockIdx.z;
    const float* s = src + (size_t)e * R * C;
    unsigned short* d = dst + (size_t)e * R * C;
    int tx = threadIdx.x, ty = threadIdx.y;  // 32 x 8
    int c0 = blockIdx.x * 32, r0 = blockIdx.y * 32;
#pragma unroll
    for (int i = 0; i < 4; ++i)
        tile[ty + i * 8][tx] = s[(size_t)(r0 + ty + i * 8) * C + c0 + tx];
    __syncthreads();
#pragma unroll
    for (int i = 0; i < 4; ++i)
        d[(size_t)(c0 + ty + i * 8) * R + r0 + tx] = f2b(tile[tx][ty + i * 8]);
}

// ---------------- fused up/gate GEMM + silu epilogue (global_load_lds staging) ----------------
__global__ __launch_bounds__(256, 2) void gemm_upgate_kernel(
        const unsigned short* __restrict__ Xg,
        const unsigned short* __restrict__ wTu,   // [E][F][H] (k-major)
        const unsigned short* __restrict__ wTg,
        unsigned short* __restrict__ inner,       // [TOTROWS][F]
        const int* __restrict__ tileExp, const int* __restrict__ tileM0,
        const int* __restrict__ off, const int* __restrict__ cnt) {
    __shared__ __align__(16) unsigned short la[128 * 32];
    __shared__ __align__(16) unsigned short lbu[128 * 32];
    __shared__ __align__(16) unsigned short lbg[128 * 32];
    int bt = blockIdx.y;
    int e = tileExp[bt];
    if (e < 0) return;
    int m0 = tileM0[bt];
    int r0 = off[e] + m0;
    int valid = cnt[e] - m0;
    int f0 = blockIdx.x * 128;
    const unsigned short* bu = wTu + (size_t)e * F_DIM * H_DIM + (size_t)f0 * H_DIM;
    const unsigned short* bg = wTg + (size_t)e * F_DIM * H_DIM + (size_t)f0 * H_DIM;
    int tid = threadIdx.x;
    int lane = tid & 63, wid = tid >> 6;
    int wm = wid >> 1, wn = wid & 1;
    int l16 = lane & 15, quad = lane >> 4;
    int lrow = lane >> 2, kc = lane & 3;   // each wave instr covers 16 rows x 64B

    // per-lane global srcs (advance by 32 elems per K-step); per-wave uniform LDS dsts
    int rA0 = (wid * 2 + 0) * 16 + lrow;
    int rA1 = (wid * 2 + 1) * 16 + lrow;
    const unsigned short* gA0 = Xg + (size_t)(r0 + rA0) * H_DIM + kc * 8;
    const unsigned short* gA1 = Xg + (size_t)(r0 + rA1) * H_DIM + kc * 8;
    const unsigned short* gU0 = bu + (size_t)rA0 * H_DIM + kc * 8;
    const unsigned short* gU1 = bu + (size_t)rA1 * H_DIM + kc * 8;
    const unsigned short* gG0 = bg + (size_t)rA0 * H_DIM + kc * 8;
    const unsigned short* gG1 = bg + (size_t)rA1 * H_DIM + kc * 8;
    unsigned short* pA0 = &la[(wid * 2 + 0) * 512];
    unsigned short* pA1 = &la[(wid * 2 + 1) * 512];
    unsigned short* pU0 = &lbu[(wid * 2 + 0) * 512];
    unsigned short* pU1 = &lbu[(wid * 2 + 1) * 512];
    unsigned short* pG0 = &lbg[(wid * 2 + 0) * 512];
    unsigned short* pG1 = &lbg[(wid * 2 + 1) * 512];

    f32x4 accU[4][4], accG[4][4];
#pragma unroll
    for (int i = 0; i < 4; ++i)
#pragma unroll
        for (int j = 0; j < 4; ++j) { accU[i][j] = (f32x4)0.f; accG[i][j] = (f32x4)0.f; }

    for (int k0 = 0; k0 < H_DIM; k0 += 32) {
        __syncthreads();
        gload16(gA0, pA0); gload16(gA1, pA1);
        gload16(gU0, pU0); gload16(gU1, pU1);
        gload16(gG0, pG0); gload16(gG1, pG1);
        gA0 += 32; gA1 += 32; gU0 += 32; gU1 += 32; gG0 += 32; gG1 += 32;
        __syncthreads();
        bf16x8 af[4], bfu[4], bfg[4];
#pragma unroll
        for (int i = 0; i < 4; ++i)
            af[i] = *(const bf16x8*)&la[(wm * 64 + i * 16 + l16) * 32 + quad * 8];
#pragma unroll
        for (int j = 0; j < 4; ++j) {
            bfu[j] = *(const bf16x8*)&lbu[(wn * 64 + j * 16 + l16) * 32 + quad * 8];
            bfg[j] = *(const bf16x8*)&lbg[(wn * 64 + j * 16 + l16) * 32 + quad * 8];
        }
#pragma unroll
        for (int i = 0; i < 4; ++i)
#pragma unroll
            for (int j = 0; j < 4; ++j) {
                accU[i][j] = __builtin_amdgcn_mfma_f32_16x16x32_bf16(af[i], bfu[j], accU[i][j], 0, 0, 0);
                accG[i][j] = __builtin_amdgcn_mfma_f32_16x16x32_bf16(af[i], bfg[j], accG[i][j], 0, 0, 0);
            }
    }
#pragma unroll
    for (int i = 0; i < 4; ++i) {
#pragma unroll
        for (int rr = 0; rr < 4; ++rr) {
            int ml = wm * 64 + i * 16 + quad * 4 + rr;
            if (ml >= valid) continue;
            size_t base = (size_t)(r0 + ml) * F_DIM + f0;
#pragma unroll
            for (int j = 0; j < 4; ++j) {
                float u = accU[i][j][rr];
                float g = accG[i][j][rr];
                float v = u / (1.f + expf(-u)) * g;   // silu(up) * gate
                inner[base + wn * 64 + j * 16 + l16] = f2b(v);
            }
        }
    }
}

// ---------------- down GEMM + weighted atomic scatter (global_load_lds staging) ----------------
__global__ __launch_bounds__(256, 2) void gemm_down_kernel(
        const unsigned short* __restrict__ inner,  // [TOTROWS][F]
        const unsigned short* __restrict__ wTd,    // [E][H][F] (k-major)
        float* __restrict__ out,
        const int* __restrict__ tileExp, const int* __restrict__ tileM0,
        const int* __restrict__ off, const int* __restrict__ cnt,
        const int* __restrict__ rowTok, const float* __restrict__ rowWgt) {
    __shared__ __align__(16) unsigned short la[128 * 32];
    __shared__ __align__(16) unsigned short lb[128 * 32];
    int bt = blockIdx.y;
    int e = tileExp[bt];
    if (e < 0) return;
    int m0 = tileM0[bt];
    int r0 = off[e] + m0;
    int valid = cnt[e] - m0;
    int h0 = blockIdx.x * 128;
    const unsigned short* bp = wTd + (size_t)e * H_DIM * F_DIM + (size_t)h0 * F_DIM;
    int tid = threadIdx.x;
    int lane = tid & 63, wid = tid >> 6;
    int wm = wid >> 1, wn = wid & 1;
    int l16 = lane & 15, quad = lane >> 4;
    int lrow = lane >> 2, kc = lane & 3;

    int rA0 = (wid * 2 + 0) * 16 + lrow;
    int rA1 = (wid * 2 + 1) * 16 + lrow;
    const unsigned short* gA0 = inner + (size_t)(r0 + rA0) * F_DIM + kc * 8;
    const unsigned short* gA1 = inner + (size_t)(r0 + rA1) * F_DIM + kc * 8;
    const unsigned short* gB0 = bp + (size_t)rA0 * F_DIM + kc * 8;
    const unsigned short* gB1 = bp + (size_t)rA1 * F_DIM + kc * 8;
    unsigned short* pA0 = &la[(wid * 2 + 0) * 512];
    unsigned short* pA1 = &la[(wid * 2 + 1) * 512];
    unsigned short* pB0 = &lb[(wid * 2 + 0) * 512];
    unsigned short* pB1 = &lb[(wid * 2 + 1) * 512];

    f32x4 acc[4][4];
#pragma unroll
    for (int i = 0; i < 4; ++i)
#pragma unroll
        for (int j = 0; j < 4; ++j) acc[i][j] = (f32x4)0.f;

    for (int k0 = 0; k0 < F_DIM; k0 += 32) {
        __syncthreads();
        gload16(gA0, pA0); gload16(gA1, pA1);
        gload16(gB0, pB0); gload16(gB1, pB1);
        gA0 += 32; gA1 += 32; gB0 += 32; gB1 += 32;
        __syncthreads();
        bf16x8 af[4], bf[4];
#pragma unroll
        for (int i = 0; i < 4; ++i)
            af[i] = *(const bf16x8*)&la[(wm * 64 + i * 16 + l16) * 32 + quad * 8];
#pragma unroll
        for (int j = 0; j < 4; ++j)
            bf[j] = *(const bf16x8*)&lb[(wn * 64 + j * 16 + l16) * 32 + quad * 8];
#pragma unroll
        for (int i = 0; i < 4; ++i)
#pragma unroll
            for (int j = 0; j < 4; ++j)
                acc[i][j] = __builtin_amdgcn_mfma_f32_16x16x32_bf16(af[i], bf[j], acc[i][j], 0, 0, 0);
    }
#pragma unroll
    for (int i = 0; i < 4; ++i) {
#pragma unroll
        for (int rr = 0; rr < 4; ++rr) {
            int ml = wm * 64 + i * 16 + quad * 4 + rr;
            if (ml >= valid) continue;
            int gr = r0 + ml;
            int t = rowTok[gr];
            float w = rowWgt[gr];
            float* orow = out + (size_t)t * H_DIM + h0;
#pragma unroll
            for (int j = 0; j < 4; ++j)
                atomicAdd(&orow[wn * 64 + j * 16 + l16], w * acc[i][j][rr]);
        }
    }
}

extern "C" void kernel_launch(void* const* d_in, const int* in_sizes, int n_in,
                              void* d_out, int out_size, void* d_ws, size_t ws_size,
                              hipStream_t stream) {
    const float* x      = (const float*)d_in[0];
    const float* gw     = (const float*)d_in[1];
    const float* w_up   = (const float*)d_in[2];
    const float* w_gate = (const float*)d_in[3];
    const float* w_down = (const float*)d_in[4];
    float* out = (float*)d_out;

    char* ws = (char*)d_ws;
    size_t o = 0;
    unsigned short* wTu = (unsigned short*)(ws + o); o += (size_t)NEXP * F_DIM * H_DIM * 2;
    unsigned short* wTg = (unsigned short*)(ws + o); o += (size_t)NEXP * F_DIM * H_DIM * 2;
    unsigned short* wTd = (unsigned short*)(ws + o); o += (size_t)NEXP * H_DIM * F_DIM * 2;
    unsigned short* Xg  = (unsigned short*)(ws + o); o += (size_t)TOTROWS * H_DIM * 2;
    unsigned short* inner = (unsigned short*)(ws + o); o += (size_t)TOTROWS * F_DIM * 2;
    int*   rowTok = (int*)(ws + o);   o += TOTROWS * 4;
    float* rowWgt = (float*)(ws + o); o += TOTROWS * 4;
    int*   sel    = (int*)(ws + o);   o += T_TOK * 2 * 4;
    float* selw   = (float*)(ws + o); o += T_TOK * 2 * 4;
    int*   cnt    = (int*)(ws + o);   o += 8 * 4;   // cnt[8] then fill[8] contiguous
    int*   fill   = (int*)(ws + o);   o += 8 * 4;
    int*   off_   = (int*)(ws + o);   o += 8 * 4;
    int*   tileExp = (int*)(ws + o);  o += MAXTILES * 4;
    int*   tileM0  = (int*)(ws + o);  o += MAXTILES * 4;

    zero_kernel<<<4096, 256, 0, stream>>>(out, cnt);
    router_kernel<<<T_TOK, 64, 0, stream>>>(x, gw, sel, selw, cnt);
    scan_kernel<<<1, 64, 0, stream>>>(cnt, off_, tileExp, tileM0);
    scatter_kernel<<<T_TOK / 256, 256, 0, stream>>>(sel, selw, off_, fill, rowTok, rowWgt);
    gather_kernel<<<TOTROWS, 256, 0, stream>>>(x, rowTok, Xg);
    dim3 tb(32, 8, 1);
    transpose_cvt_kernel<<<dim3(F_DIM / 32, H_DIM / 32, NEXP), tb, 0, stream>>>(w_up, wTu, H_DIM, F_DIM);
    transpose_cvt_kernel<<<dim3(F_DIM / 32, H_DIM / 32, NEXP), tb, 0, stream>>>(w_gate, wTg, H_DIM, F_DIM);
    transpose_cvt_kernel<<<dim3(H_DIM / 32, F_DIM / 32, NEXP), tb, 0, stream>>>(w_down, wTd, F_DIM, H_DIM);
    gemm_upgate_kernel<<<dim3(F_DIM / 128, 72), 256, 0, stream>>>(Xg, wTu, wTg, inner, tileExp, tileM0, off_, cnt);
    gemm_down_kernel<<<dim3(H_DIM / 128, 72), 256, 0, stream>>>(inner, wTd, out, tileExp, tileM0, off_, cnt, rowTok, rowWgt);
}

// Round 3
// 566.613 us; speedup vs baseline: 1.1579x; 1.0338x over previous
//
#include <hip/hip_runtime.h>
#include <hip/hip_bf16.h>

typedef __bf16 bf16x8 __attribute__((ext_vector_type(8)));
typedef float f32x4 __attribute__((ext_vector_type(4)));

#define T_TOK 4096
#define H_DIM 1024
#define F_DIM 2048
#define NEXP 8
#define TOTROWS 8192   // T_TOK * TOP_K, always exact (top-2 distinct experts)
#define MAXTILES 80

__device__ inline unsigned short f2b(float f) {
    unsigned int u = __float_as_uint(f);
    unsigned int r = (u + 0x7fffu + ((u >> 16) & 1u)) >> 16;
    return (unsigned short)r;
}

// async global->LDS, 16B per lane. LDS dst = wave-uniform base + lane*16.
__device__ inline void gload16(const void* g, void* l) {
    __builtin_amdgcn_global_load_lds(
        (const __attribute__((address_space(1))) unsigned int*)g,
        (__attribute__((address_space(3))) unsigned int*)l,
        16, 0, 0);
}

// ---------------- router: logits -> softmax -> top2 -> renorm (4 tokens/block) ----------------
__global__ __launch_bounds__(256) void router_kernel(const float* __restrict__ x,
                                                     const float* __restrict__ gw,
                                                     int* __restrict__ sel, float* __restrict__ selw,
                                                     int* __restrict__ cnt) {
    int t = blockIdx.x * 4 + (threadIdx.x >> 6);
    int lane = threadIdx.x & 63;
    float acc[8] = {0.f,0.f,0.f,0.f,0.f,0.f,0.f,0.f};
    const float* xr = x + (size_t)t * H_DIM;
    for (int h = lane; h < H_DIM; h += 64) {
        float xv = xr[h];
        const float4* g = (const float4*)(gw + h * 8);
        float4 g0 = g[0], g1 = g[1];
        acc[0] += xv * g0.x; acc[1] += xv * g0.y; acc[2] += xv * g0.z; acc[3] += xv * g0.w;
        acc[4] += xv * g1.x; acc[5] += xv * g1.y; acc[6] += xv * g1.z; acc[7] += xv * g1.w;
    }
#pragma unroll
    for (int off = 32; off >= 1; off >>= 1)
#pragma unroll
        for (int e = 0; e < 8; ++e)
            acc[e] += __shfl_down(acc[e], off);
    if (lane == 0) {
        float mx = acc[0];
#pragma unroll
        for (int e = 1; e < 8; ++e) mx = fmaxf(mx, acc[e]);
        float p[8]; float s = 0.f;
#pragma unroll
        for (int e = 0; e < 8; ++e) { p[e] = expf(acc[e] - mx); s += p[e]; }
        float inv_s = 1.f / s;
#pragma unroll
        for (int e = 0; e < 8; ++e) p[e] *= inv_s;
        int e1 = 0; float p1 = p[0];
#pragma unroll
        for (int e = 1; e < 8; ++e) if (p[e] > p1) { p1 = p[e]; e1 = e; }
        int e2 = -1; float p2 = -1.f;
#pragma unroll
        for (int e = 0; e < 8; ++e) { if (e == e1) continue; if (p[e] > p2) { p2 = p[e]; e2 = e; } }
        float inv = 1.f / (p1 + p2);
        sel[t * 2 + 0] = e1; sel[t * 2 + 1] = e2;
        selw[t * 2 + 0] = p1 * inv; selw[t * 2 + 1] = p2 * inv;
        atomicAdd(&cnt[e1], 1); atomicAdd(&cnt[e2], 1);
    }
}

// ---------------- prefix scan + tile table ----------------
__global__ void scan_kernel(const int* __restrict__ cnt, int* __restrict__ off,
                            int* __restrict__ tileExp, int* __restrict__ tileM0) {
    if (blockIdx.x == 0 && threadIdx.x == 0) {
        int o = 0;
        for (int e = 0; e < NEXP; ++e) { off[e] = o; o += cnt[e]; }
        int nt = 0;
        for (int e = 0; e < NEXP; ++e)
            for (int m0 = 0; m0 < cnt[e]; m0 += 128) { tileExp[nt] = e; tileM0[nt] = m0; nt++; }
        for (int i = nt; i < MAXTILES; ++i) { tileExp[i] = -1; tileM0[i] = 0; }
    }
}

// ---------------- scatter: build compacted row lists + token->row map ----------------
__global__ __launch_bounds__(256) void scatter_kernel(const int* __restrict__ sel,
                                                      const float* __restrict__ selw,
                                                      const int* __restrict__ off,
                                                      int* __restrict__ fill,
                                                      int* __restrict__ rowTok, float* __restrict__ rowWgt,
                                                      int* __restrict__ tokRow) {
    int t = blockIdx.x * 256 + threadIdx.x;
    if (t >= T_TOK) return;
#pragma unroll
    for (int k = 0; k < 2; ++k) {
        int e = sel[t * 2 + k];
        int slot = atomicAdd(&fill[e], 1);
        int r = off[e] + slot;
        rowTok[r] = t;
        rowWgt[r] = selw[t * 2 + k];
        tokRow[t * 2 + k] = r;
    }
}

// ---------------- gather: x rows (fp32) -> Xg (bf16), compacted order ----------------
__global__ __launch_bounds__(256) void gather_kernel(const float* __restrict__ x,
                                                     const int* __restrict__ rowTok,
                                                     unsigned short* __restrict__ Xg) {
    int r = blockIdx.x;
    int t = rowTok[r];
    const float4* src = (const float4*)(x + (size_t)t * H_DIM);
    int i = threadIdx.x;
    float4 v = src[i];
    ushort4 o;
    o.x = f2b(v.x); o.y = f2b(v.y); o.z = f2b(v.z); o.w = f2b(v.w);
    ((ushort4*)(Xg + (size_t)r * H_DIM))[i] = o;
}

// ---------------- fused transpose+cvt for all 3 weight tensors ----------------
// z=0: w_up [H][F] -> wTu [F][H];  z=1: w_gate;  z=2: w_down [F][H] -> wTd [H][F]
__global__ __launch_bounds__(256) void transpose_cvt_kernel(
        const float* __restrict__ w_up, const float* __restrict__ w_gate,
        const float* __restrict__ w_down,
        unsigned short* __restrict__ wTu, unsigned short* __restrict__ wTg,
        unsigned short* __restrict__ wTd) {
    __shared__ unsigned short lt[64 * 68];  // [c][r], pad 68: b64-aligned rows
    int z = blockIdx.z;
    int e = blockIdx.y;
    const float* src; unsigned short* dst; int R, C, tr, tc;
    if (z == 0)      { src = w_up;   dst = wTu; R = H_DIM; C = F_DIM; }
    else if (z == 1) { src = w_gate; dst = wTg; R = H_DIM; C = F_DIM; }
    else             { src = w_down; dst = wTd; R = F_DIM; C = H_DIM; }
    if (R == H_DIM) { tc = blockIdx.x & 31; tr = blockIdx.x >> 5; }   // 16x32 tiles
    else            { tc = blockIdx.x & 15; tr = blockIdx.x >> 4; }   // 32x16 tiles
    const float* s = src + (size_t)e * H_DIM * F_DIM;
    unsigned short* d = dst + (size_t)e * H_DIM * F_DIM;
    int r0 = tr * 64, c0 = tc * 64;
    int tid = threadIdx.x;
    int fc = tid & 15, row = tid >> 4;      // read: 16 float4-cols x 16 rows/pass
#pragma unroll
    for (int i = 0; i < 4; ++i) {
        int r = row + i * 16;
        float4 v = *(const float4*)(s + (size_t)(r0 + r) * C + c0 + fc * 4);
        lt[(fc * 4 + 0) * 68 + r] = f2b(v.x);
        lt[(fc * 4 + 1) * 68 + r] = f2b(v.y);
        lt[(fc * 4 + 2) * 68 + r] = f2b(v.z);
        lt[(fc * 4 + 3) * 68 + r] = f2b(v.w);
    }
    __syncthreads();
    int ch = tid & 7, cc = tid >> 3;        // write: 8 chunks x 32 c-rows/pass
#pragma unroll
    for (int i = 0; i < 2; ++i) {
        int c = cc + i * 32;
        uint2 lo = *(const uint2*)&lt[c * 68 + ch * 8];
        uint2 hi = *(const uint2*)&lt[c * 68 + ch * 8 + 4];
        uint4 o = make_uint4(lo.x, lo.y, hi.x, hi.y);
        *(uint4*)(d + (size_t)(c0 + c) * R + r0 + ch * 8) = o;
    }
}

// ---------------- fused up/gate GEMM + silu epilogue (swizzled global_load_lds) ----------------
__global__ __launch_bounds__(256, 2) void gemm_upgate_kernel(
        const unsigned short* __restrict__ Xg,
        const unsigned short* __restrict__ wTu,   // [E][F][H] (k-major)
        const unsigned short* __restrict__ wTg,
        unsigned short* __restrict__ inner,       // [TOTROWS][F]
        const int* __restrict__ tileExp, const int* __restrict__ tileM0,
        const int* __restrict__ off, const int* __restrict__ cnt) {
    __shared__ __align__(16) unsigned short la[128 * 32];
    __shared__ __align__(16) unsigned short lbu[128 * 32];
    __shared__ __align__(16) unsigned short lbg[128 * 32];
    int bt = blockIdx.y;
    int e = tileExp[bt];
    if (e < 0) return;
    int m0 = tileM0[bt];
    int r0 = off[e] + m0;
    int valid = cnt[e] - m0;
    int f0 = blockIdx.x * 128;
    const unsigned short* bu = wTu + (size_t)e * F_DIM * H_DIM + (size_t)f0 * H_DIM;
    const unsigned short* bg = wTg + (size_t)e * F_DIM * H_DIM + (size_t)f0 * H_DIM;
    int tid = threadIdx.x;
    int lane = tid & 63, wid = tid >> 6;
    int wm = wid >> 1, wn = wid & 1;
    int l16 = lane & 15, quad = lane >> 4;
    int lrow = lane >> 2;
    int kcs = ((lane & 3) ^ ((lane >> 3) & 3)) * 8;   // XOR bank swizzle (source side)
    int psw = (quad ^ ((l16 >> 1) & 3)) * 8;          // matching fragment position

    int rA0 = (wid * 2 + 0) * 16 + lrow;
    int rA1 = (wid * 2 + 1) * 16 + lrow;
    const unsigned short* gA0 = Xg + (size_t)(r0 + rA0) * H_DIM + kcs;
    const unsigned short* gA1 = Xg + (size_t)(r0 + rA1) * H_DIM + kcs;
    const unsigned short* gU0 = bu + (size_t)rA0 * H_DIM + kcs;
    const unsigned short* gU1 = bu + (size_t)rA1 * H_DIM + kcs;
    const unsigned short* gG0 = bg + (size_t)rA0 * H_DIM + kcs;
    const unsigned short* gG1 = bg + (size_t)rA1 * H_DIM + kcs;
    unsigned short* pA0 = &la[(wid * 2 + 0) * 512];
    unsigned short* pA1 = &la[(wid * 2 + 1) * 512];
    unsigned short* pU0 = &lbu[(wid * 2 + 0) * 512];
    unsigned short* pU1 = &lbu[(wid * 2 + 1) * 512];
    unsigned short* pG0 = &lbg[(wid * 2 + 0) * 512];
    unsigned short* pG1 = &lbg[(wid * 2 + 1) * 512];

    f32x4 accU[4][4], accG[4][4];
#pragma unroll
    for (int i = 0; i < 4; ++i)
#pragma unroll
        for (int j = 0; j < 4; ++j) { accU[i][j] = (f32x4)0.f; accG[i][j] = (f32x4)0.f; }

    for (int k0 = 0; k0 < H_DIM; k0 += 32) {
        __syncthreads();
        gload16(gA0, pA0); gload16(gA1, pA1);
        gload16(gU0, pU0); gload16(gU1, pU1);
        gload16(gG0, pG0); gload16(gG1, pG1);
        gA0 += 32; gA1 += 32; gU0 += 32; gU1 += 32; gG0 += 32; gG1 += 32;
        __syncthreads();
        bf16x8 af[4], bfu[4], bfg[4];
#pragma unroll
        for (int i = 0; i < 4; ++i)
            af[i] = *(const bf16x8*)&la[(wm * 64 + i * 16 + l16) * 32 + psw];
#pragma unroll
        for (int j = 0; j < 4; ++j) {
            bfu[j] = *(const bf16x8*)&lbu[(wn * 64 + j * 16 + l16) * 32 + psw];
            bfg[j] = *(const bf16x8*)&lbg[(wn * 64 + j * 16 + l16) * 32 + psw];
        }
#pragma unroll
        for (int i = 0; i < 4; ++i)
#pragma unroll
            for (int j = 0; j < 4; ++j) {
                accU[i][j] = __builtin_amdgcn_mfma_f32_16x16x32_bf16(af[i], bfu[j], accU[i][j], 0, 0, 0);
                accG[i][j] = __builtin_amdgcn_mfma_f32_16x16x32_bf16(af[i], bfg[j], accG[i][j], 0, 0, 0);
            }
    }
#pragma unroll
    for (int i = 0; i < 4; ++i) {
#pragma unroll
        for (int rr = 0; rr < 4; ++rr) {
            int ml = wm * 64 + i * 16 + quad * 4 + rr;
            if (ml >= valid) continue;
            size_t base = (size_t)(r0 + ml) * F_DIM + f0;
#pragma unroll
            for (int j = 0; j < 4; ++j) {
                float u = accU[i][j][rr];
                float g = accG[i][j][rr];
                float v = u / (1.f + expf(-u)) * g;   // silu(up) * gate
                inner[base + wn * 64 + j * 16 + l16] = f2b(v);
            }
        }
    }
}

// ---------------- down GEMM -> scaled fp32 partial rows (no atomics) ----------------
__global__ __launch_bounds__(256, 2) void gemm_down_kernel(
        const unsigned short* __restrict__ inner,  // [TOTROWS][F]
        const unsigned short* __restrict__ wTd,    // [E][H][F] (k-major)
        float* __restrict__ part,                  // [TOTROWS][H]
        const int* __restrict__ tileExp, const int* __restrict__ tileM0,
        const int* __restrict__ off, const int* __restrict__ cnt,
        const float* __restrict__ rowWgt) {
    __shared__ __align__(16) unsigned short la[128 * 32];
    __shared__ __align__(16) unsigned short lb[128 * 32];
    int bt = blockIdx.y;
    int e = tileExp[bt];
    if (e < 0) return;
    int m0 = tileM0[bt];
    int r0 = off[e] + m0;
    int valid = cnt[e] - m0;
    int h0 = blockIdx.x * 128;
    const unsigned short* bp = wTd + (size_t)e * H_DIM * F_DIM + (size_t)h0 * F_DIM;
    int tid = threadIdx.x;
    int lane = tid & 63, wid = tid >> 6;
    int wm = wid >> 1, wn = wid & 1;
    int l16 = lane & 15, quad = lane >> 4;
    int lrow = lane >> 2;
    int kcs = ((lane & 3) ^ ((lane >> 3) & 3)) * 8;
    int psw = (quad ^ ((l16 >> 1) & 3)) * 8;

    int rA0 = (wid * 2 + 0) * 16 + lrow;
    int rA1 = (wid * 2 + 1) * 16 + lrow;
    const unsigned short* gA0 = inner + (size_t)(r0 + rA0) * F_DIM + kcs;
    const unsigned short* gA1 = inner + (size_t)(r0 + rA1) * F_DIM + kcs;
    const unsigned short* gB0 = bp + (size_t)rA0 * F_DIM + kcs;
    const unsigned short* gB1 = bp + (size_t)rA1 * F_DIM + kcs;
    unsigned short* pA0 = &la[(wid * 2 + 0) * 512];
    unsigned short* pA1 = &la[(wid * 2 + 1) * 512];
    unsigned short* pB0 = &lb[(wid * 2 + 0) * 512];
    unsigned short* pB1 = &lb[(wid * 2 + 1) * 512];

    f32x4 acc[4][4];
#pragma unroll
    for (int i = 0; i < 4; ++i)
#pragma unroll
        for (int j = 0; j < 4; ++j) acc[i][j] = (f32x4)0.f;

    for (int k0 = 0; k0 < F_DIM; k0 += 32) {
        __syncthreads();
        gload16(gA0, pA0); gload16(gA1, pA1);
        gload16(gB0, pB0); gload16(gB1, pB1);
        gA0 += 32; gA1 += 32; gB0 += 32; gB1 += 32;
        __syncthreads();
        bf16x8 af[4], bf[4];
#pragma unroll
        for (int i = 0; i < 4; ++i)
            af[i] = *(const bf16x8*)&la[(wm * 64 + i * 16 + l16) * 32 + psw];
#pragma unroll
        for (int j = 0; j < 4; ++j)
            bf[j] = *(const bf16x8*)&lb[(wn * 64 + j * 16 + l16) * 32 + psw];
#pragma unroll
        for (int i = 0; i < 4; ++i)
#pragma unroll
            for (int j = 0; j < 4; ++j)
                acc[i][j] = __builtin_amdgcn_mfma_f32_16x16x32_bf16(af[i], bf[j], acc[i][j], 0, 0, 0);
    }
#pragma unroll
    for (int i = 0; i < 4; ++i) {
#pragma unroll
        for (int rr = 0; rr < 4; ++rr) {
            int ml = wm * 64 + i * 16 + quad * 4 + rr;
            if (ml >= valid) continue;
            int gr = r0 + ml;
            float w = rowWgt[gr];
            float* orow = part + (size_t)gr * H_DIM + h0;
#pragma unroll
            for (int j = 0; j < 4; ++j)
                orow[wn * 64 + j * 16 + l16] = w * acc[i][j][rr];
        }
    }
}

// ---------------- combine: out[t] = part[r1] + part[r2] ----------------
__global__ __launch_bounds__(256) void combine_kernel(const float* __restrict__ part,
                                                      const int* __restrict__ tokRow,
                                                      float* __restrict__ out) {
    int t = blockIdx.x;
    int r1 = tokRow[t * 2 + 0], r2 = tokRow[t * 2 + 1];
    int i = threadIdx.x;
    float4 a = ((const float4*)(part + (size_t)r1 * H_DIM))[i];
    float4 b = ((const float4*)(part + (size_t)r2 * H_DIM))[i];
    float4 o;
    o.x = a.x + b.x; o.y = a.y + b.y; o.z = a.z + b.z; o.w = a.w + b.w;
    ((float4*)(out + (size_t)t * H_DIM))[i] = o;
}

extern "C" void kernel_launch(void* const* d_in, const int* in_sizes, int n_in,
                              void* d_out, int out_size, void* d_ws, size_t ws_size,
                              hipStream_t stream) {
    const float* x      = (const float*)d_in[0];
    const float* gw     = (const float*)d_in[1];
    const float* w_up   = (const float*)d_in[2];
    const float* w_gate = (const float*)d_in[3];
    const float* w_down = (const float*)d_in[4];
    float* out = (float*)d_out;

    char* ws = (char*)d_ws;
    size_t o = 0;
    unsigned short* wTu = (unsigned short*)(ws + o); o += (size_t)NEXP * F_DIM * H_DIM * 2;
    unsigned short* wTg = (unsigned short*)(ws + o); o += (size_t)NEXP * F_DIM * H_DIM * 2;
    unsigned short* wTd = (unsigned short*)(ws + o); o += (size_t)NEXP * H_DIM * F_DIM * 2;
    unsigned short* Xg  = (unsigned short*)(ws + o); o += (size_t)TOTROWS * H_DIM * 2;
    unsigned short* inner = (unsigned short*)(ws + o); o += (size_t)TOTROWS * F_DIM * 2;
    o += 512 * 1024;  // pad: GEMM staging tail-row overreads past inner stay in ws
    int*   rowTok = (int*)(ws + o);   o += TOTROWS * 4;
    float* rowWgt = (float*)(ws + o); o += TOTROWS * 4;
    int*   tokRow = (int*)(ws + o);   o += T_TOK * 2 * 4;
    int*   sel    = (int*)(ws + o);   o += T_TOK * 2 * 4;
    float* selw   = (float*)(ws + o); o += T_TOK * 2 * 4;
    int*   cnt    = (int*)(ws + o);   o += 8 * 4;   // cnt[8] then fill[8] contiguous
    int*   fill   = (int*)(ws + o);   o += 8 * 4;
    int*   off_   = (int*)(ws + o);   o += 8 * 4;
    int*   tileExp = (int*)(ws + o);  o += MAXTILES * 4;
    int*   tileM0  = (int*)(ws + o);  o += MAXTILES * 4;
    // part[TOTROWS][H] fp32 aliases wTu+wTg (dead after gemm_upgate; stream-serial)
    float* part = (float*)wTu;

    hipMemsetAsync(cnt, 0, 16 * 4, stream);
    router_kernel<<<T_TOK / 4, 256, 0, stream>>>(x, gw, sel, selw, cnt);
    scan_kernel<<<1, 64, 0, stream>>>(cnt, off_, tileExp, tileM0);
    scatter_kernel<<<T_TOK / 256, 256, 0, stream>>>(sel, selw, off_, fill, rowTok, rowWgt, tokRow);
    gather_kernel<<<TOTROWS, 256, 0, stream>>>(x, rowTok, Xg);
    transpose_cvt_kernel<<<dim3(512, NEXP, 3), 256, 0, stream>>>(w_up, w_gate, w_down, wTu, wTg, wTd);
    gemm_upgate_kernel<<<dim3(F_DIM / 128, 72), 256, 0, stream>>>(Xg, wTu, wTg, inner, tileExp, tileM0, off_, cnt);
    gemm_down_kernel<<<dim3(H_DIM / 128, 72), 256, 0, stream>>>(inner, wTd, part, tileExp, tileM0, off_, cnt, rowWgt);
    combine_kernel<<<T_TOK, 256, 0, stream>>>(part, tokRow, out);
}